// Round 3
// baseline (1675.690 us; speedup 1.0000x reference)
//
#include <hip/hip_runtime.h>
#include <math.h>

#define NN 75000
#define NE 150000
#define H 44
#define HS 48            // sliced row stride: real col c lives at c + c/11 (pads at 11,23,35,47)
#define EDIM 10
#define NFRAG 15000
#define NGRAPH 1500

typedef const float* __restrict__ cfp;
typedef float* __restrict__ fpt;
typedef const int* __restrict__ cip;
typedef int* __restrict__ ipt;

__device__ __forceinline__ float relu_(float v){ return v>0.f?v:0.f; }
__device__ __forceinline__ float sigmoid_(float v){ return 1.f/(1.f+expf(-v)); }

// ---------------- CSR build (dst-major) ----------------
__global__ __launch_bounds__(256) void k_hist(cip ei, ipt cnt){
    int e = blockIdx.x*256 + threadIdx.x;
    if(e>=NE) return;
    atomicAdd(&cnt[ei[NE+e]], 1);
}

__global__ __launch_bounds__(1024) void k_scan1(cip cnt, ipt incl, ipt bsum){
    __shared__ int sd[1024];
    int i = blockIdx.x*1024 + threadIdx.x;
    int v = (i<NN)? cnt[i] : 0;
    sd[threadIdx.x]=v;
    __syncthreads();
    for(int off=1; off<1024; off<<=1){
        int t = (threadIdx.x>=off)? sd[threadIdx.x-off] : 0;
        __syncthreads();
        sd[threadIdx.x]+=t;
        __syncthreads();
    }
    if(i<NN) incl[i]=sd[threadIdx.x];
    if(threadIdx.x==1023) bsum[blockIdx.x]=sd[1023];
}

__global__ void k_scan2(ipt bsum, int nblk){
    if(threadIdx.x==0 && blockIdx.x==0){
        int run=0;
        for(int b=0;b<nblk;b++){ int t=bsum[b]; bsum[b]=run; run+=t; }
    }
}

__global__ __launch_bounds__(1024) void k_scan3(cip incl, cip bsum, ipt rowptr){
    int i = blockIdx.x*1024 + threadIdx.x;
    if(i==0) rowptr[0]=0;
    if(i<NN) rowptr[i+1] = incl[i] + bsum[i>>10];
}

__global__ __launch_bounds__(256) void k_scatter(cip ei, cip rowptr, ipt cur, ipt eidx){
    int e = blockIdx.x*256 + threadIdx.x;
    if(e>=NE) return;
    int d = ei[NE+e];
    int pos = rowptr[d] + atomicAdd(&cur[d],1);
    eidx[pos]=e;
}

// ---------------- out = relu(x @ W0 + b0), sliced-48 output ----------------
__global__ __launch_bounds__(256) void k_in(cfp x, cfp W0, cfp b0, fpt out){
    __shared__ float sW[H*H];
    __shared__ float sb[H];
    for(int i=threadIdx.x;i<H*H;i+=256) sW[i]=W0[i];
    if(threadIdx.x<H) sb[threadIdx.x]=b0[threadIdx.x];
    __syncthreads();
    int n = blockIdx.x*256 + threadIdx.x;
    if(n>=NN) return;
    float xv[H];
    const float4* xp = (const float4*)(x + (size_t)n*H);
    #pragma unroll
    for(int i=0;i<11;i++){ float4 v=xp[i]; xv[4*i]=v.x; xv[4*i+1]=v.y; xv[4*i+2]=v.z; xv[4*i+3]=v.w; }
    float acc[H];
    #pragma unroll
    for(int o=0;o<H;o++) acc[o]=sb[o];
    #pragma unroll
    for(int h=0;h<H;h++){
        float xh = xv[h];
        const float4* wr = (const float4*)(sW + h*H);
        #pragma unroll
        for(int o=0;o<11;o++){
            float4 w = wr[o];
            acc[4*o]+=xh*w.x; acc[4*o+1]+=xh*w.y; acc[4*o+2]+=xh*w.z; acc[4*o+3]+=xh*w.w;
        }
    }
    #pragma unroll
    for(int o=0;o<H;o++) acc[o]=relu_(acc[o]);
    float* row = out + (size_t)n*HS;
    #pragma unroll
    for(int s=0;s<4;s++){
        float4* p=(float4*)(row + s*12);
        p[0]=make_float4(acc[11*s+0],acc[11*s+1],acc[11*s+2],acc[11*s+3]);
        p[1]=make_float4(acc[11*s+4],acc[11*s+5],acc[11*s+6],acc[11*s+7]);
        p[2]=make_float4(acc[11*s+8],acc[11*s+9],acc[11*s+10],0.f);
    }
}

// ---------------- b2 = out @ be2(HxH view), sliced in/out ----------------
#define NB2 256
__global__ __launch_bounds__(256,3) void k_b2(cfp out, cfp be2, fpt b2){
    __shared__ float ovT[HS*NB2];
    int tid=threadIdx.x, lane=tid&63;
    int og = __builtin_amdgcn_readfirstlane(tid>>6);
    size_t base=(size_t)blockIdx.x*NB2;
    { size_t n=base+tid; size_t nc = n<NN? n : NN-1;
      const float4* orow=(const float4*)(out + nc*HS);
      #pragma unroll
      for(int i=0;i<12;i++){ float4 v=orow[i];
        ovT[(4*i+0)*NB2+tid]=v.x; ovT[(4*i+1)*NB2+tid]=v.y;
        ovT[(4*i+2)*NB2+tid]=v.z; ovT[(4*i+3)*NB2+tid]=v.w; }
    }
    __syncthreads();
    float m[4][11];
    #pragma unroll
    for(int j=0;j<4;j++)
        #pragma unroll
        for(int o=0;o<11;o++) m[j][o]=0.f;
    const float* wog = be2 + og*11;
    #pragma unroll
    for(int h=0;h<H;h++){
        int hl = h + h/11;
        const float4* ovp=(const float4*)(ovT + hl*NB2 + lane*4);
        float4 ov=ovp[0];
        #pragma unroll
        for(int o=0;o<11;o++){
            float w = wog[h*H+o];
            m[0][o]+=ov.x*w; m[1][o]+=ov.y*w; m[2][o]+=ov.z*w; m[3][o]+=ov.w*w;
        }
    }
    size_t n0 = base + (size_t)lane*4;
    #pragma unroll
    for(int j=0;j<4;j++){
        size_t n=n0+j;
        if(n<NN){
            float4* p=(float4*)(b2 + n*HS + og*12);
            p[0]=make_float4(m[j][0],m[j][1],m[j][2],m[j][3]);
            p[1]=make_float4(m[j][4],m[j][5],m[j][6],m[j][7]);
            p[2]=make_float4(m[j][8],m[j][9],m[j][10],0.f);
        }
    }
}

// ---------------- t = relu(edge_attr @ We1 + be1) ----------------
__global__ __launch_bounds__(256) void k_edge(cfp ea, cfp We1, cfp be1, fpt t){
    __shared__ float sW[EDIM*EDIM];
    __shared__ float sb[EDIM];
    if(threadIdx.x<EDIM*EDIM) sW[threadIdx.x]=We1[threadIdx.x];
    if(threadIdx.x<EDIM) sb[threadIdx.x]=be1[threadIdx.x];
    __syncthreads();
    int e = blockIdx.x*256 + threadIdx.x;
    if(e>=NE) return;
    float acc[EDIM];
    #pragma unroll
    for(int j=0;j<EDIM;j++) acc[j]=sb[j];
    #pragma unroll
    for(int k=0;k<EDIM;k++){
        float a = ea[(size_t)e*EDIM + k];
        #pragma unroll
        for(int j=0;j<EDIM;j++) acc[j]+=a*sW[k*EDIM+j];
    }
    #pragma unroll
    for(int j=0;j<EDIM;j++) t[(size_t)e*EDIM+j]=relu_(acc[j]);
}

// ---------------- per-edge message: 4 edges x 11 outputs per thread ----------------
#define EBM 256
__global__ __launch_bounds__(256,2) void k_msg(cfp out, cfp b2, cfp t, cfp We2, cip ei, fpt msg){
    __shared__ float ovT[HS*EBM];     // [sliced-h][edge]
    __shared__ float tT[EDIM*EBM];    // [k][edge]
    int tid=threadIdx.x, lane=tid&63;
    int og = __builtin_amdgcn_readfirstlane(tid>>6);
    size_t base=(size_t)blockIdx.x*EBM;
    { size_t e=base+tid; size_t ec = e<NE? e : NE-1;
      int s = ei[ec];
      const float4* orow=(const float4*)(out + (size_t)s*HS);
      #pragma unroll
      for(int i=0;i<12;i++){ float4 v=orow[i];
        ovT[(4*i+0)*EBM+tid]=v.x; ovT[(4*i+1)*EBM+tid]=v.y;
        ovT[(4*i+2)*EBM+tid]=v.z; ovT[(4*i+3)*EBM+tid]=v.w; }
      const float2* trow=(const float2*)(t + ec*EDIM);
      #pragma unroll
      for(int i=0;i<5;i++){ float2 v=trow[i]; tT[(2*i+0)*EBM+tid]=v.x; tT[(2*i+1)*EBM+tid]=v.y; }
    }
    __syncthreads();
    size_t e0 = base + (size_t)lane*4;
    int srcj[4];
    #pragma unroll
    for(int j=0;j<4;j++){ size_t e=e0+j; srcj[j]=ei[e<NE? e : NE-1]; }
    float m[4][11];
    #pragma unroll
    for(int j=0;j<4;j++){
        const float4* br=(const float4*)(b2 + (size_t)srcj[j]*HS + og*12);
        float4 A=br[0],B=br[1],C=br[2];
        m[j][0]=A.x; m[j][1]=A.y; m[j][2]=A.z; m[j][3]=A.w;
        m[j][4]=B.x; m[j][5]=B.y; m[j][6]=B.z; m[j][7]=B.w;
        m[j][8]=C.x; m[j][9]=C.y; m[j][10]=C.z;
    }
    const float* wog = We2 + og*11;
    for(int k=0;k<EDIM;k++){
        const float4* tp=(const float4*)(tT + k*EBM + lane*4);
        float4 t4=tp[0];
        const float* wk = wog + k*(H*H);
        #pragma unroll
        for(int h=0;h<H;h++){
            int hl = h + h/11;
            const float4* ovp=(const float4*)(ovT + hl*EBM + lane*4);
            float4 ov=ovp[0];
            float z0=t4.x*ov.x, z1=t4.y*ov.y, z2=t4.z*ov.z, z3=t4.w*ov.w;
            #pragma unroll
            for(int o=0;o<11;o++){
                float w = wk[h*H+o];
                m[0][o]+=z0*w; m[1][o]+=z1*w; m[2][o]+=z2*w; m[3][o]+=z3*w;
            }
        }
    }
    #pragma unroll
    for(int j=0;j<4;j++){
        size_t e=e0+j;
        if(e<NE){
            float4* p=(float4*)(msg + e*HS + og*12);
            p[0]=make_float4(m[j][0],m[j][1],m[j][2],m[j][3]);
            p[1]=make_float4(m[j][4],m[j][5],m[j][6],m[j][7]);
            p[2]=make_float4(m[j][8],m[j][9],m[j][10],0.f);
        }
    }
}

// ---------------- gather + combine ----------------
#define NBC 128
__global__ __launch_bounds__(256,3) void k_comb(cfp out, cfp msg, cip rowptr, cip eidx,
                                                cfp root, cfp conv_b, cfp Wm, cfp bm, fpt out_nxt){
    __shared__ float ovT[HS*NBC];
    __shared__ float mT[HS*NBC];
    int tid=threadIdx.x, lane=tid&63;
    int og = __builtin_amdgcn_readfirstlane(tid>>6);
    size_t base=(size_t)blockIdx.x*NBC;
    { int nl=tid>>1, half=tid&1;
      size_t n=base+nl; size_t nc = n<NN? n : NN-1;
      const float4* orow=(const float4*)(out + nc*HS + half*24);
      #pragma unroll
      for(int i=0;i<6;i++){ float4 v=orow[i];
        ovT[(half*24+4*i+0)*NBC+nl]=v.x; ovT[(half*24+4*i+1)*NBC+nl]=v.y;
        ovT[(half*24+4*i+2)*NBC+nl]=v.z; ovT[(half*24+4*i+3)*NBC+nl]=v.w; }
    }
    __syncthreads();
    size_t n0 = base + (size_t)lane*2;
    float m[2][11];
    #pragma unroll
    for(int j=0;j<2;j++)
        #pragma unroll
        for(int o=0;o<11;o++) m[j][o]=conv_b[og*11+o];
    #pragma unroll
    for(int j=0;j<2;j++){
        size_t n=n0+j; size_t nc = n<NN? n : NN-1;
        int st=rowptr[nc], en=rowptr[nc+1];
        for(int idx=st; idx<en; idx++){
            int e=eidx[idx];
            const float4* p=(const float4*)(msg + (size_t)e*HS + og*12);
            float4 A=p[0],B=p[1],C=p[2];
            m[j][0]+=A.x; m[j][1]+=A.y; m[j][2]+=A.z; m[j][3]+=A.w;
            m[j][4]+=B.x; m[j][5]+=B.y; m[j][6]+=B.z; m[j][7]+=B.w;
            m[j][8]+=C.x; m[j][9]+=C.y; m[j][10]+=C.z;
        }
    }
    const float* rog = root + og*11;
    #pragma unroll
    for(int h=0;h<H;h++){
        int hl = h + h/11;
        const float2* ovp=(const float2*)(ovT + hl*NBC + lane*2);
        float2 ov=ovp[0];
        #pragma unroll
        for(int o=0;o<11;o++){
            float w = rog[h*H+o];
            m[0][o]+=ov.x*w; m[1][o]+=ov.y*w;
        }
    }
    #pragma unroll
    for(int j=0;j<2;j++)
        #pragma unroll
        for(int o=0;o<11;o++) m[j][o]=relu_(m[j][o]);
    #pragma unroll
    for(int j=0;j<2;j++)
        #pragma unroll
        for(int o=0;o<11;o++) mT[(og*12+o)*NBC + lane*2+j]=m[j][o];
    __syncthreads();
    float no[2][11];
    #pragma unroll
    for(int j=0;j<2;j++)
        #pragma unroll
        for(int o=0;o<11;o++) no[j][o]=bm[og*11+o];
    const float* wmog = Wm + og*11;
    #pragma unroll
    for(int h=0;h<H;h++){
        int hl = h + h/11;
        const float2* mp=(const float2*)(mT + hl*NBC + lane*2);
        const float2* ovp=(const float2*)(ovT + hl*NBC + lane*2);
        float2 mh=mp[0], ov=ovp[0];
        #pragma unroll
        for(int o=0;o<11;o++){
            float a = wmog[h*H+o];
            float b = wmog[(H+h)*H+o];
            no[0][o]+=mh.x*a+ov.x*b;
            no[1][o]+=mh.y*a+ov.y*b;
        }
    }
    #pragma unroll
    for(int j=0;j<2;j++){
        size_t n=n0+j;
        if(n<NN){
            float4* p=(float4*)(out_nxt + n*HS + og*12);
            p[0]=make_float4(no[j][0],no[j][1],no[j][2],no[j][3]);
            p[1]=make_float4(no[j][4],no[j][5],no[j][6],no[j][7]);
            p[2]=make_float4(no[j][8],no[j][9],no[j][10],0.f);
        }
    }
}

// ---------------- fragment stage: 50 frags (250 nodes) per block ----------------
__global__ __launch_bounds__(256,2) void k_frag(cfp out, cfp x, cfp Wc1, cfp bc1,
                                                fpt frag, fpt z, fpt colstat){
    __shared__ float nd[250*45];
    __shared__ float frS[50*45];
    __shared__ float sW[H*H];
    int tid=threadIdx.x;
    for(int i=tid;i<H*H;i+=256) sW[i]=Wc1[i];
    if(tid<250){
        int n = blockIdx.x*250 + tid;
        float v[H];
        const float4* xp=(const float4*)(x + (size_t)n*H);
        #pragma unroll
        for(int i=0;i<11;i++){ float4 a=xp[i]; v[4*i]=a.x; v[4*i+1]=a.y; v[4*i+2]=a.z; v[4*i+3]=a.w; }
        const float4* orow=(const float4*)(out + (size_t)n*HS);
        #pragma unroll
        for(int s=0;s<4;s++){
            float4 A=orow[3*s+0],B=orow[3*s+1],C=orow[3*s+2];
            v[11*s+0]+=A.x; v[11*s+1]+=A.y; v[11*s+2]+=A.z; v[11*s+3]+=A.w;
            v[11*s+4]+=B.x; v[11*s+5]+=B.y; v[11*s+6]+=B.z; v[11*s+7]+=B.w;
            v[11*s+8]+=C.x; v[11*s+9]+=C.y; v[11*s+10]+=C.z;
        }
        float ss=0.f;
        #pragma unroll
        for(int o=0;o<H;o++) ss+=v[o]*v[o];
        float inv = 1.f/fmaxf(sqrtf(ss),1e-12f);
        #pragma unroll
        for(int o=0;o<H;o++) nd[tid*45+o]=v[o]*inv;
    }
    __syncthreads();
    if(tid<50){
        float fr[H];
        #pragma unroll
        for(int o=0;o<H;o++) fr[o]=0.f;
        for(int j=0;j<5;j++){
            int r=tid*5+j;
            #pragma unroll
            for(int o=0;o<H;o++) fr[o]+=nd[r*45+o];
        }
        #pragma unroll
        for(int o=0;o<H;o++){ fr[o]*=0.2f; frS[tid*45+o]=fr[o]; }
        int f = blockIdx.x*50 + tid;
        float4* fw=(float4*)(frag + (size_t)f*H);
        #pragma unroll
        for(int i=0;i<11;i++) fw[i]=make_float4(fr[4*i],fr[4*i+1],fr[4*i+2],fr[4*i+3]);
    }
    __syncthreads();
    int fl=tid>>2, q=tid&3;
    int flc = fl<50? fl : 0;
    bool fv = fl<50;
    float zr[11];
    #pragma unroll
    for(int o=0;o<11;o++) zr[o]=bc1[q*11+o];
    for(int h=0;h<H;h++){
        float fh = frS[flc*45+h];
        #pragma unroll
        for(int o=0;o<11;o++) zr[o]+=fh*sW[h*H+q*11+o];
    }
    #pragma unroll
    for(int o=0;o<11;o++) if(!fv) zr[o]=0.f;
    if(fv){
        int f = blockIdx.x*50 + fl;
        #pragma unroll
        for(int o=0;o<11;o++) z[(size_t)f*H + q*11+o]=zr[o];
    }
    #pragma unroll
    for(int o=0;o<11;o++){
        float s=zr[o], sq=zr[o]*zr[o];
        #pragma unroll
        for(int d=4;d<64;d<<=1){ s+=__shfl_xor(s,d); sq+=__shfl_xor(sq,d); }
        if((tid&63)<4){
            atomicAdd(colstat + q*11+o, s);
            atomicAdd(colstat + H + q*11+o, sq);
        }
    }
}

// ---------------- batchnorm + classifier ----------------
__global__ __launch_bounds__(256) void k_bnw(cfp z, cfp colstat, cfp bng, cfp bnb, cfp Wc2, cfp bc2, fpt w, fpt pres){
    int f = blockIdx.x*256 + threadIdx.x;
    bool valid = f < NFRAG;
    int fc = valid ? f : NFRAG-1;
    float s = 0.f;
    #pragma unroll
    for(int o=0;o<H;o++){
        float mean = colstat[o]*(1.f/NFRAG);
        float var  = colstat[H+o]*(1.f/NFRAG) - mean*mean;
        float zb = (z[(size_t)fc*H+o]-mean)*rsqrtf(var+1e-5f)*bng[o]+bnb[o];
        s += relu_(zb)*Wc2[o];
    }
    float wv = sigmoid_(s + bc2[0]);
    if(valid) w[f]=wv;
    unsigned long long msk = __ballot(valid && (wv > 0.5f));
    if((threadIdx.x&63)==0) atomicAdd(pres,(float)__popcll(msk));
}

// ---------------- per-graph: stats + noisy + KL, one wave per graph ----------------
__global__ __launch_bounds__(64) void k_graph(cfp frag, cfp w, cfp noise, fpt sub, fpt klg){
    int g = blockIdx.x;
    int o = threadIdx.x;
    bool act = o < H;
    int oc = act ? o : 0;
    float frv[10];
    #pragma unroll
    for(int j=0;j<10;j++) frv[j] = act ? frag[(size_t)(10*g+j)*H + oc] : 0.f;
    float gs=0.f, gq=0.f;
    #pragma unroll
    for(int j=0;j<10;j++){ gs+=frv[j]; gq+=frv[j]*frv[j]; }
    float gmean = gs*0.1f;
    float gvar  = (gq - 10.f*gmean*gmean)*(1.f/9.f);
    float gstd  = sqrtf(fmaxf(gvar,0.f));
    float se    = gstd + 1e-7f;
    float c     = act ? (gstd/se)*(gstd/se) : 0.f;
    float C = c;
    #pragma unroll
    for(int dlt=32;dlt>0;dlt>>=1) C+=__shfl_xor(C,dlt);
    float subacc=0.f, B=0.f, Sln=0.f;
    #pragma unroll
    for(int j=0;j<10;j++){
        float lp = w[10*g+j];
        float ln = 1.f-lp;
        Sln += ln*ln;
        float nm = lp*frv[j] + ln*gmean;
        float ns = ln*gstd;
        float ny = nm + (act ? noise[(size_t)(10*g+j)*H + oc] : 0.f)*ns;
        subacc += ny;
        float dd = (nm-gmean)/se;
        B += dd*dd;
    }
    if(act) sub[(size_t)g*H+o] = subacc*0.1f;
    float Bv = act ? B : 0.f;
    #pragma unroll
    for(int dlt=32;dlt>0;dlt>>=1) Bv+=__shfl_xor(Bv,dlt);
    if(o==0) klg[g] = 0.5f*C*Sln + Bv;
}

// ---------------- per-graph MLP head -> pred ----------------
__global__ __launch_bounds__(256) void k_pred(cfp sub, cfp Wp1, cfp bp1, cfp Wp2, cfp bp2,
                                              cfp Wp3, cfp bp3, fpt outp){
    __shared__ float ssub[H];
    __shared__ float sh1[256];
    __shared__ float sh2[128];
    int g = blockIdx.x; int tid = threadIdx.x;
    if(tid<H) ssub[tid] = sub[(size_t)g*H+tid];
    __syncthreads();
    float a = bp1[tid];
    for(int o=0;o<H;o++) a += ssub[o]*Wp1[(size_t)o*256+tid];
    sh1[tid]=relu_(a);
    __syncthreads();
    if(tid<128){
        float b = bp2[tid];
        for(int i=0;i<256;i++) b += sh1[i]*Wp2[(size_t)i*128+tid];
        sh2[tid]=relu_(b);
    }
    __syncthreads();
    if(tid<64){
        float s = sh2[tid]*Wp3[tid] + sh2[tid+64]*Wp3[tid+64];
        #pragma unroll
        for(int dlt=32;dlt>0;dlt>>=1) s+=__shfl_xor(s,dlt);
        if(tid==0) outp[g]=sigmoid_(s+bp3[0]);
    }
}

// ---------------- kl.mean + preserve_rate ----------------
__global__ void k_final(cfp klg, cfp pres, fpt outp){
    float s = 0.f;
    for(int i=threadIdx.x;i<NGRAPH;i+=256) s+=klg[i];
    __shared__ float red[4];
    #pragma unroll
    for(int dlt=32;dlt>0;dlt>>=1) s+=__shfl_xor(s,dlt);
    int wid = threadIdx.x>>6;
    if((threadIdx.x&63)==0) red[wid]=s;
    __syncthreads();
    if(threadIdx.x==0){
        float tot = red[0]+red[1]+red[2]+red[3];
        outp[NGRAPH]   = tot/(float)(NGRAPH*H);
        outp[NGRAPH+1] = pres[0]/(float)NFRAG;
    }
}

extern "C" void kernel_launch(void* const* d_in, const int* in_sizes, int n_in,
                              void* d_out, int out_size, void* d_ws, size_t ws_size,
                              hipStream_t stream) {
    (void)in_sizes; (void)n_in; (void)out_size; (void)ws_size;
    const float* x        =(const float*)d_in[0];
    const float* edge_attr=(const float*)d_in[1];
    const float* noise    =(const float*)d_in[2];
    const float* W0       =(const float*)d_in[3];
    const float* b0       =(const float*)d_in[4];
    const float* We1      =(const float*)d_in[5];
    const float* be1      =(const float*)d_in[6];
    const float* We2      =(const float*)d_in[7];
    const float* be2      =(const float*)d_in[8];
    const float* root     =(const float*)d_in[9];
    const float* conv_b   =(const float*)d_in[10];
    const float* Wm       =(const float*)d_in[11];
    const float* bm       =(const float*)d_in[12];
    const float* Wc1      =(const float*)d_in[13];
    const float* bc1      =(const float*)d_in[14];
    const float* bng      =(const float*)d_in[15];
    const float* bnb      =(const float*)d_in[16];
    const float* Wc2      =(const float*)d_in[17];
    const float* bc2      =(const float*)d_in[18];
    const float* Wp1      =(const float*)d_in[19];
    const float* bp1      =(const float*)d_in[20];
    const float* Wp2      =(const float*)d_in[21];
    const float* bp2      =(const float*)d_in[22];
    const float* Wp3      =(const float*)d_in[23];
    const float* bp3      =(const float*)d_in[24];
    const int*   ei       =(const int*)d_in[25];

    float* ws = (float*)d_ws;
    const size_t NHS = (size_t)NN*HS;
    float* out_a  = ws;
    float* out_b  = out_a + NHS;
    float* b2_a   = out_b + NHS;
    float* b2_b   = b2_a + NHS;
    float* tbuf   = b2_b + NHS;
    float* msgbuf = tbuf + (size_t)NE*EDIM;
    float* frag   = msgbuf + (size_t)NE*HS;
    float* zbuf   = frag + (size_t)NFRAG*H;
    float* wv     = zbuf + (size_t)NFRAG*H;
    float* sub    = wv + NFRAG;
    float* klg    = sub + (size_t)NGRAPH*H;
    int*   rowptr = (int*)(klg + NGRAPH);
    int*   eidx   = rowptr + (NN+1);
    int*   bsum   = eidx + NE;
    int*   incl   = bsum + 128;
    int*   cnt    = incl + NN;
    int*   cur    = cnt + NN;
    float* colstat= (float*)(cur + NN);
    float* pres   = colstat + 2*H;

    hipMemsetAsync(cnt, 0, (size_t)(2*NN + 2*H + 8)*sizeof(float), stream);

    const int nb_n  = (NN + 255)/256;
    const int nb_e  = (NE + 255)/256;
    const int nb_f  = (NFRAG + 255)/256;
    const int nblk  = (NN + 1023)/1024;
    const int nb_c  = (NN + NBC-1)/NBC;

    k_hist   <<<nb_e,256,0,stream>>>(ei, cnt);
    k_scan1  <<<nblk,1024,0,stream>>>(cnt, incl, bsum);
    k_scan2  <<<1,64,0,stream>>>(bsum, nblk);
    k_scan3  <<<nblk,1024,0,stream>>>(incl, bsum, rowptr);
    k_scatter<<<nb_e,256,0,stream>>>(ei, rowptr, cur, eidx);

    k_in  <<<nb_n,256,0,stream>>>(x, W0, b0, out_a);
    k_b2  <<<nb_n,256,0,stream>>>(out_a, be2, b2_a);
    k_edge<<<nb_e,256,0,stream>>>(edge_attr, We1, be1, tbuf);

    float* cur_o = out_a; float* cur_b = b2_a;
    float* nxt_o = out_b; float* nxt_b = b2_b;
    for(int it=0; it<3; ++it){
        k_msg <<<nb_e,256,0,stream>>>(cur_o, cur_b, tbuf, We2, ei, msgbuf);
        k_comb<<<nb_c,256,0,stream>>>(cur_o, msgbuf, rowptr, eidx, root, conv_b, Wm, bm, nxt_o);
        if(it<2) k_b2<<<nb_n,256,0,stream>>>(nxt_o, be2, nxt_b);
        float* tp;
        tp=cur_o; cur_o=nxt_o; nxt_o=tp;
        tp=cur_b; cur_b=nxt_b; nxt_b=tp;
    }

    k_frag <<<300,256,0,stream>>>(cur_o, x, Wc1, bc1, frag, zbuf, colstat);
    k_bnw  <<<nb_f,256,0,stream>>>(zbuf, colstat, bng, bnb, Wc2, bc2, wv, pres);
    k_graph<<<NGRAPH,64,0,stream>>>(frag, wv, noise, sub, klg);
    k_pred <<<NGRAPH,256,0,stream>>>(sub, Wp1, bp1, Wp2, bp2, Wp3, bp3, (float*)d_out);
    k_final<<<1,256,0,stream>>>(klg, pres, (float*)d_out);
}

// Round 8
// 1367.086 us; speedup vs baseline: 1.2257x; 1.2257x over previous
//
#include <hip/hip_runtime.h>
#include <math.h>

#define NN 75000
#define NE 150000
#define H 44
#define HS 48            // sliced row stride: real col c at c + c/11 (pads at 11,23,35,47)
#define EDIM 10
#define NFRAG 15000
#define NGRAPH 1500

typedef const float* __restrict__ cfp;
typedef float* __restrict__ fpt;
typedef const int* __restrict__ cip;
typedef int* __restrict__ ipt;

__device__ __forceinline__ float relu_(float v){ return v>0.f?v:0.f; }
__device__ __forceinline__ float sigmoid_(float v){ return 1.f/(1.f+expf(-v)); }

// ---------------- CSR build (dst-major) ----------------
__global__ __launch_bounds__(256) void k_hist(cip ei, ipt cnt){
    int e = blockIdx.x*256 + threadIdx.x;
    if(e>=NE) return;
    atomicAdd(&cnt[ei[NE+e]], 1);
}

__global__ __launch_bounds__(1024) void k_scan1(cip cnt, ipt incl, ipt bsum){
    __shared__ int sd[1024];
    int i = blockIdx.x*1024 + threadIdx.x;
    int v = (i<NN)? cnt[i] : 0;
    sd[threadIdx.x]=v;
    __syncthreads();
    for(int off=1; off<1024; off<<=1){
        int t = (threadIdx.x>=off)? sd[threadIdx.x-off] : 0;
        __syncthreads();
        sd[threadIdx.x]+=t;
        __syncthreads();
    }
    if(i<NN) incl[i]=sd[threadIdx.x];
    if(threadIdx.x==1023) bsum[blockIdx.x]=sd[1023];
}

__global__ void k_scan2(ipt bsum, int nblk){
    if(threadIdx.x==0 && blockIdx.x==0){
        int run=0;
        for(int b=0;b<nblk;b++){ int t=bsum[b]; bsum[b]=run; run+=t; }
    }
}

__global__ __launch_bounds__(1024) void k_scan3(cip incl, cip bsum, ipt rowptr){
    int i = blockIdx.x*1024 + threadIdx.x;
    if(i==0) rowptr[0]=0;
    if(i<NN) rowptr[i+1] = incl[i] + bsum[i>>10];
}

__global__ __launch_bounds__(256) void k_scatter(cip ei, cip rowptr, ipt cur, ipt eidx){
    int e = blockIdx.x*256 + threadIdx.x;
    if(e>=NE) return;
    int d = ei[NE+e];
    int pos = rowptr[d] + atomicAdd(&cur[d],1);
    eidx[pos]=e;
}

// sort each node's edge segment ascending (canonical order: deterministic + matches numpy)
__global__ __launch_bounds__(256) void k_sortcsr(cip rowptr, ipt eidx){
    int n = blockIdx.x*256 + threadIdx.x;
    if(n>=NN) return;
    int st=rowptr[n], en=rowptr[n+1];
    for(int i=st+1;i<en;i++){
        int v=eidx[i]; int j=i-1;
        while(j>=st && eidx[j]>v){ eidx[j+1]=eidx[j]; j--; }
        eidx[j+1]=v;
    }
}

// permute edge data into CSR order: srcP[pos]=src, tP[pos][12]=t (padded)
__global__ __launch_bounds__(256) void k_perm(cip eidx, cip ei, cfp t, ipt srcP, fpt tP){
    int p = blockIdx.x*256+threadIdx.x;
    if(p>=NE) return;
    int e = eidx[p];
    srcP[p] = ei[e];
    #pragma unroll
    for(int k=0;k<EDIM;k++) tP[(size_t)p*12+k] = t[(size_t)e*EDIM+k];
    tP[(size_t)p*12+10]=0.f; tP[(size_t)p*12+11]=0.f;
}

// padded weight table: WextP[(c*48+hh)*48+oo], zeros on pad rows/cols; c=10 -> be2
__global__ __launch_bounds__(256) void k_wprep(cfp We2, cfp be2, fpt WextP){
    int idx = blockIdx.x*256 + threadIdx.x;
    if(idx>=11*48*48) return;
    int oo = idx%48, hh=(idx/48)%48, c=idx/(48*48);
    float v=0.f;
    if(oo%12!=11 && hh%12!=11){
        int o = oo - oo/12, h = hh - hh/12;
        v = (c<10)? We2[(size_t)c*1936 + h*44 + o] : be2[h*44+o];
    }
    WextP[idx]=v;
}

// ---------------- out = relu(x @ W0 + b0), sliced-48 output ----------------
__global__ __launch_bounds__(256) void k_in(cfp x, cfp W0, cfp b0, fpt out){
    __shared__ float sW[H*H];
    __shared__ float sb[H];
    for(int i=threadIdx.x;i<H*H;i+=256) sW[i]=W0[i];
    if(threadIdx.x<H) sb[threadIdx.x]=b0[threadIdx.x];
    __syncthreads();
    int n = blockIdx.x*256 + threadIdx.x;
    if(n>=NN) return;
    float xv[H];
    const float4* xp = (const float4*)(x + (size_t)n*H);
    #pragma unroll
    for(int i=0;i<11;i++){ float4 v=xp[i]; xv[4*i]=v.x; xv[4*i+1]=v.y; xv[4*i+2]=v.z; xv[4*i+3]=v.w; }
    float acc[H];
    #pragma unroll
    for(int o=0;o<H;o++) acc[o]=sb[o];
    #pragma unroll
    for(int h=0;h<H;h++){
        float xh = xv[h];
        const float4* wr = (const float4*)(sW + h*H);
        #pragma unroll
        for(int o=0;o<11;o++){
            float4 w = wr[o];
            acc[4*o]+=xh*w.x; acc[4*o+1]+=xh*w.y; acc[4*o+2]+=xh*w.z; acc[4*o+3]+=xh*w.w;
        }
    }
    #pragma unroll
    for(int o=0;o<H;o++) acc[o]=relu_(acc[o]);
    float* row = out + (size_t)n*HS;
    #pragma unroll
    for(int s=0;s<4;s++){
        float4* p=(float4*)(row + s*12);
        p[0]=make_float4(acc[11*s+0],acc[11*s+1],acc[11*s+2],acc[11*s+3]);
        p[1]=make_float4(acc[11*s+4],acc[11*s+5],acc[11*s+6],acc[11*s+7]);
        p[2]=make_float4(acc[11*s+8],acc[11*s+9],acc[11*s+10],0.f);
    }
}

// ---------------- t = relu(edge_attr @ We1 + be1) ----------------
__global__ __launch_bounds__(256) void k_edge(cfp ea, cfp We1, cfp be1, fpt t){
    __shared__ float sW[EDIM*EDIM];
    __shared__ float sb[EDIM];
    if(threadIdx.x<EDIM*EDIM) sW[threadIdx.x]=We1[threadIdx.x];
    if(threadIdx.x<EDIM) sb[threadIdx.x]=be1[threadIdx.x];
    __syncthreads();
    int e = blockIdx.x*256 + threadIdx.x;
    if(e>=NE) return;
    float acc[EDIM];
    #pragma unroll
    for(int j=0;j<EDIM;j++) acc[j]=sb[j];
    #pragma unroll
    for(int k=0;k<EDIM;k++){
        float a = ea[(size_t)e*EDIM + k];
        #pragma unroll
        for(int j=0;j<EDIM;j++) acc[j]+=a*sW[k*EDIM+j];
    }
    #pragma unroll
    for(int j=0;j<EDIM;j++) t[(size_t)e*EDIM+j]=relu_(acc[j]);
}

// ---------------- fused gather+contract: agg[n,o] = sum_c sum_h R[n,c,h] * Wext[c,h,o] ----------------
// Wave og gathers its h-slice (real h = og*11+i); contracts on the fly into P[44] (all o);
// 4 waves' partials tree-summed in LDS (deterministic); no intermediate in HBM; pure fp32.
__global__ __launch_bounds__(256,3) void k_Ragg(cfp out, cip rowptr, cip srcP, cfp tP, cfp WextP, fpt agg){
    __shared__ float sP[4*44*64];
    int tid=threadIdx.x, lane=tid&63;
    int og = __builtin_amdgcn_readfirstlane(tid>>6);
    int n = blockIdx.x*64 + lane;
    int st=0, en=0;
    if(n<NN){ st=rowptr[n]; en=rowptr[n+1]; }
    float P[44];
    #pragma unroll
    for(int o=0;o<44;o++) P[o]=0.f;

    // ---- pass A: channels 0..5 ----
    {
        float acc[6][11];
        #pragma unroll
        for(int c=0;c<6;c++)
            #pragma unroll
            for(int i=0;i<11;i++) acc[c][i]=0.f;
        for(int j=st;j<en;j++){
            int s = srcP[j];
            const float4* tp4=(const float4*)(tP + (size_t)j*12);
            float4 ta=tp4[0];
            float2 tb2=*(const float2*)(tP + (size_t)j*12 + 4);
            float tk[6] = {ta.x,ta.y,ta.z,ta.w, tb2.x,tb2.y};
            const float4* ov4=(const float4*)(out + (size_t)s*HS + og*12);
            float4 oa=ov4[0], ob=ov4[1], oc=ov4[2];
            float ovv[11] = {oa.x,oa.y,oa.z,oa.w, ob.x,ob.y,ob.z,ob.w, oc.x,oc.y,oc.z};
            #pragma unroll
            for(int c=0;c<6;c++)
                #pragma unroll
                for(int i=0;i<11;i++) acc[c][i]+=tk[c]*ovv[i];
        }
        #pragma unroll
        for(int c=0;c<6;c++){
            #pragma unroll
            for(int i=0;i<11;i++){
                float a = acc[c][i];
                const float4* wr=(const float4*)(WextP + ((size_t)c*48 + og*12 + i)*48);
                #pragma unroll
                for(int q=0;q<4;q++){
                    float4 wA=wr[3*q], wB=wr[3*q+1], wC=wr[3*q+2];
                    P[q*11+0]+=a*wA.x; P[q*11+1]+=a*wA.y; P[q*11+2]+=a*wA.z; P[q*11+3]+=a*wA.w;
                    P[q*11+4]+=a*wB.x; P[q*11+5]+=a*wB.y; P[q*11+6]+=a*wB.z; P[q*11+7]+=a*wB.w;
                    P[q*11+8]+=a*wC.x; P[q*11+9]+=a*wC.y; P[q*11+10]+=a*wC.z;
                }
            }
        }
    }
    // ---- pass B: channels 6..9 plus ones-channel (10) ----
    {
        float acc[5][11];
        #pragma unroll
        for(int c=0;c<5;c++)
            #pragma unroll
            for(int i=0;i<11;i++) acc[c][i]=0.f;
        for(int j=st;j<en;j++){
            int s = srcP[j];
            const float4* tp4=(const float4*)(tP + (size_t)j*12 + 4);
            float4 tb=tp4[0];   // t[4..7]
            float2 tc2=*(const float2*)(tP + (size_t)j*12 + 8);
            float tk[4] = {tb.z,tb.w, tc2.x,tc2.y};
            const float4* ov4=(const float4*)(out + (size_t)s*HS + og*12);
            float4 oa=ov4[0], ob=ov4[1], oc=ov4[2];
            float ovv[11] = {oa.x,oa.y,oa.z,oa.w, ob.x,ob.y,ob.z,ob.w, oc.x,oc.y,oc.z};
            #pragma unroll
            for(int c=0;c<4;c++)
                #pragma unroll
                for(int i=0;i<11;i++) acc[c][i]+=tk[c]*ovv[i];
            #pragma unroll
            for(int i=0;i<11;i++) acc[4][i]+=ovv[i];
        }
        #pragma unroll
        for(int c=0;c<5;c++){
            #pragma unroll
            for(int i=0;i<11;i++){
                float a = acc[c][i];
                const float4* wr=(const float4*)(WextP + ((size_t)(c+6)*48 + og*12 + i)*48);
                #pragma unroll
                for(int q=0;q<4;q++){
                    float4 wA=wr[3*q], wB=wr[3*q+1], wC=wr[3*q+2];
                    P[q*11+0]+=a*wA.x; P[q*11+1]+=a*wA.y; P[q*11+2]+=a*wA.z; P[q*11+3]+=a*wA.w;
                    P[q*11+4]+=a*wB.x; P[q*11+5]+=a*wB.y; P[q*11+6]+=a*wB.z; P[q*11+7]+=a*wB.w;
                    P[q*11+8]+=a*wC.x; P[q*11+9]+=a*wC.y; P[q*11+10]+=a*wC.z;
                }
            }
        }
    }
    // ---- deterministic cross-wave reduce via LDS ----
    #pragma unroll
    for(int o=0;o<44;o++) sP[((size_t)og*44+o)*64 + lane] = P[o];
    __syncthreads();
    float m[11];
    #pragma unroll
    for(int i=0;i<11;i++){
        int o = og*11+i;
        m[i] = sP[(0*44+o)*64+lane] + sP[(1*44+o)*64+lane]
             + sP[(2*44+o)*64+lane] + sP[(3*44+o)*64+lane];
    }
    if(n<NN){
        float4* p=(float4*)(agg + (size_t)n*HS + og*12);
        p[0]=make_float4(m[0],m[1],m[2],m[3]);
        p[1]=make_float4(m[4],m[5],m[6],m[7]);
        p[2]=make_float4(m[8],m[9],m[10],0.f);
    }
}

// ---------------- combine (in-place): m=relu(agg + out@root + cb); out=[m,out]@Wm+bm ----------------
#define NBC 128
__global__ __launch_bounds__(256,3) void k_comb(fpt out, cfp agg,
                                                cfp root, cfp conv_b, cfp Wm, cfp bm){
    __shared__ float ovT[HS*NBC];
    __shared__ float mT[HS*NBC];
    int tid=threadIdx.x, lane=tid&63;
    int og = __builtin_amdgcn_readfirstlane(tid>>6);
    size_t base=(size_t)blockIdx.x*NBC;
    { int nl=tid>>1, half=tid&1;
      size_t n=base+nl; size_t nc = n<NN? n : NN-1;
      const float4* orow=(const float4*)(out + nc*HS + half*24);
      #pragma unroll
      for(int i=0;i<6;i++){ float4 v=orow[i];
        ovT[(half*24+4*i+0)*NBC+nl]=v.x; ovT[(half*24+4*i+1)*NBC+nl]=v.y;
        ovT[(half*24+4*i+2)*NBC+nl]=v.z; ovT[(half*24+4*i+3)*NBC+nl]=v.w; }
    }
    __syncthreads();
    size_t n0 = base + (size_t)lane*2;
    float m[2][11];
    #pragma unroll
    for(int j=0;j<2;j++){
        size_t n=n0+j; size_t nc = n<NN? n : NN-1;
        const float4* ap=(const float4*)(agg + nc*HS + og*12);
        float4 A=ap[0],B=ap[1],C=ap[2];
        m[j][0]=A.x; m[j][1]=A.y; m[j][2]=A.z; m[j][3]=A.w;
        m[j][4]=B.x; m[j][5]=B.y; m[j][6]=B.z; m[j][7]=B.w;
        m[j][8]=C.x; m[j][9]=C.y; m[j][10]=C.z;
        #pragma unroll
        for(int o=0;o<11;o++) m[j][o]+=conv_b[og*11+o];
    }
    const float* rog = root + og*11;
    #pragma unroll
    for(int h=0;h<H;h++){
        int hl = h + h/11;
        const float2* ovp=(const float2*)(ovT + hl*NBC + lane*2);
        float2 ov=ovp[0];
        #pragma unroll
        for(int o=0;o<11;o++){
            float w = rog[h*H+o];
            m[0][o]+=ov.x*w; m[1][o]+=ov.y*w;
        }
    }
    #pragma unroll
    for(int j=0;j<2;j++)
        #pragma unroll
        for(int o=0;o<11;o++) m[j][o]=relu_(m[j][o]);
    #pragma unroll
    for(int j=0;j<2;j++)
        #pragma unroll
        for(int o=0;o<11;o++) mT[(og*12+o)*NBC + lane*2+j]=m[j][o];
    __syncthreads();
    float no[2][11];
    #pragma unroll
    for(int j=0;j<2;j++)
        #pragma unroll
        for(int o=0;o<11;o++) no[j][o]=bm[og*11+o];
    const float* wmog = Wm + og*11;
    #pragma unroll
    for(int h=0;h<H;h++){
        int hl = h + h/11;
        const float2* mp=(const float2*)(mT + hl*NBC + lane*2);
        const float2* ovp=(const float2*)(ovT + hl*NBC + lane*2);
        float2 mh=mp[0], ov=ovp[0];
        #pragma unroll
        for(int o=0;o<11;o++){
            float a = wmog[h*H+o];
            float b = wmog[(H+h)*H+o];
            no[0][o]+=mh.x*a+ov.x*b;
            no[1][o]+=mh.y*a+ov.y*b;
        }
    }
    #pragma unroll
    for(int j=0;j<2;j++){
        size_t n=n0+j;
        if(n<NN){
            float4* p=(float4*)(out + n*HS + og*12);
            p[0]=make_float4(no[j][0],no[j][1],no[j][2],no[j][3]);
            p[1]=make_float4(no[j][4],no[j][5],no[j][6],no[j][7]);
            p[2]=make_float4(no[j][8],no[j][9],no[j][10],0.f);
        }
    }
}

// ---------------- fragment stage: 50 frags (250 nodes) per block; NO global atomics ----------------
__global__ __launch_bounds__(256,2) void k_frag(cfp out, cfp x, cfp Wc1, cfp bc1,
                                                fpt frag, fpt z, fpt colpart){
    __shared__ float nd[250*45];
    __shared__ float frS[50*45];
    __shared__ float sW[H*H];
    __shared__ float sP[4*176];
    int tid=threadIdx.x;
    for(int i=tid;i<H*H;i+=256) sW[i]=Wc1[i];
    if(tid<250){
        int n = blockIdx.x*250 + tid;
        float v[H];
        const float4* xp=(const float4*)(x + (size_t)n*H);
        #pragma unroll
        for(int i=0;i<11;i++){ float4 a=xp[i]; v[4*i]=a.x; v[4*i+1]=a.y; v[4*i+2]=a.z; v[4*i+3]=a.w; }
        const float4* orow=(const float4*)(out + (size_t)n*HS);
        #pragma unroll
        for(int s=0;s<4;s++){
            float4 A=orow[3*s+0],B=orow[3*s+1],C=orow[3*s+2];
            v[11*s+0]+=A.x; v[11*s+1]+=A.y; v[11*s+2]+=A.z; v[11*s+3]+=A.w;
            v[11*s+4]+=B.x; v[11*s+5]+=B.y; v[11*s+6]+=B.z; v[11*s+7]+=B.w;
            v[11*s+8]+=C.x; v[11*s+9]+=C.y; v[11*s+10]+=C.z;
        }
        float ss=0.f;
        #pragma unroll
        for(int o=0;o<H;o++) ss+=v[o]*v[o];
        float inv = 1.f/fmaxf(sqrtf(ss),1e-12f);
        #pragma unroll
        for(int o=0;o<H;o++) nd[tid*45+o]=v[o]*inv;
    }
    __syncthreads();
    if(tid<50){
        float fr[H];
        #pragma unroll
        for(int o=0;o<H;o++) fr[o]=0.f;
        for(int j=0;j<5;j++){
            int r=tid*5+j;
            #pragma unroll
            for(int o=0;o<H;o++) fr[o]+=nd[r*45+o];
        }
        #pragma unroll
        for(int o=0;o<H;o++){ fr[o]*=0.2f; frS[tid*45+o]=fr[o]; }
        int f = blockIdx.x*50 + tid;
        float4* fw=(float4*)(frag + (size_t)f*H);
        #pragma unroll
        for(int i=0;i<11;i++) fw[i]=make_float4(fr[4*i],fr[4*i+1],fr[4*i+2],fr[4*i+3]);
    }
    __syncthreads();
    int fl=tid>>2, q=tid&3;
    int flc = fl<50? fl : 0;
    bool fv = fl<50;
    float zr[11];
    #pragma unroll
    for(int o=0;o<11;o++) zr[o]=bc1[q*11+o];
    for(int h=0;h<H;h++){
        float fh = frS[flc*45+h];
        #pragma unroll
        for(int o=0;o<11;o++) zr[o]+=fh*sW[h*H+q*11+o];
    }
    #pragma unroll
    for(int o=0;o<11;o++) if(!fv) zr[o]=0.f;
    if(fv){
        int f = blockIdx.x*50 + fl;
        #pragma unroll
        for(int o=0;o<11;o++) z[(size_t)f*H + q*11+o]=zr[o];
    }
    int wid = tid>>6;
    #pragma unroll
    for(int o=0;o<11;o++){
        float s=zr[o], sq=zr[o]*zr[o];
        #pragma unroll
        for(int d=4;d<64;d<<=1){ s+=__shfl_xor(s,d); sq+=__shfl_xor(sq,d); }
        if((tid&63)<4){
            sP[wid*176 + q*11+o] = s;
            sP[wid*176 + 88 + q*11+o] = sq;
        }
    }
    __syncthreads();
    if(tid<176){
        float s = sP[tid] + sP[176+tid] + sP[352+tid] + sP[528+tid];
        colpart[(size_t)blockIdx.x*176 + tid] = s;
    }
}

// reduce colpart -> colstat[176]
__global__ __launch_bounds__(64) void k_colred(cfp colpart, fpt colstat){
    int col = blockIdx.x;       // 176 blocks
    int tid = threadIdx.x;
    float s = 0.f;
    for(int b=tid;b<300;b+=64) s += colpart[(size_t)b*176 + col];
    #pragma unroll
    for(int d=32;d>0;d>>=1) s+=__shfl_xor(s,d);
    if(tid==0) colstat[col]=s;
}

// ---------------- batchnorm + classifier ----------------
__global__ __launch_bounds__(256) void k_bnw(cfp z, cfp colstat, cfp bng, cfp bnb, cfp Wc2, cfp bc2, fpt w, fpt pres){
    int f = blockIdx.x*256 + threadIdx.x;
    bool valid = f < NFRAG;
    int fc = valid ? f : NFRAG-1;
    float s = 0.f;
    #pragma unroll
    for(int o=0;o<H;o++){
        float mean = colstat[o]*(1.f/NFRAG);
        float var  = colstat[H+o]*(1.f/NFRAG) - mean*mean;
        float zb = (z[(size_t)fc*H+o]-mean)*rsqrtf(var+1e-5f)*bng[o]+bnb[o];
        s += relu_(zb)*Wc2[o];
    }
    float wv = sigmoid_(s + bc2[0]);
    if(valid) w[f]=wv;
    unsigned long long msk = __ballot(valid && (wv > 0.5f));
    if((threadIdx.x&63)==0) atomicAdd(pres,(float)__popcll(msk));
}

// ---------------- per-graph: stats + noisy + KL, one wave per graph ----------------
__global__ __launch_bounds__(64) void k_graph(cfp frag, cfp w, cfp noise, fpt sub, fpt klg){
    int g = blockIdx.x;
    int o = threadIdx.x;
    bool act = o < H;
    int oc = act ? o : 0;
    float frv[10];
    #pragma unroll
    for(int j=0;j<10;j++) frv[j] = act ? frag[(size_t)(10*g+j)*H + oc] : 0.f;
    float gs=0.f, gq=0.f;
    #pragma unroll
    for(int j=0;j<10;j++){ gs+=frv[j]; gq+=frv[j]*frv[j]; }
    float gmean = gs*0.1f;
    float gvar  = (gq - 10.f*gmean*gmean)*(1.f/9.f);
    float gstd  = sqrtf(fmaxf(gvar,0.f));
    float se    = gstd + 1e-7f;
    float c     = act ? (gstd/se)*(gstd/se) : 0.f;
    float C = c;
    #pragma unroll
    for(int dlt=32;dlt>0;dlt>>=1) C+=__shfl_xor(C,dlt);
    float subacc=0.f, B=0.f, Sln=0.f;
    #pragma unroll
    for(int j=0;j<10;j++){
        float lp = w[10*g+j];
        float ln = 1.f-lp;
        Sln += ln*ln;
        float nm = lp*frv[j] + ln*gmean;
        float ns = ln*gstd;
        float ny = nm + (act ? noise[(size_t)(10*g+j)*H + oc] : 0.f)*ns;
        subacc += ny;
        float dd = (nm-gmean)/se;
        B += dd*dd;
    }
    if(act) sub[(size_t)g*H+o] = subacc*0.1f;
    float Bv = act ? B : 0.f;
    #pragma unroll
    for(int dlt=32;dlt>0;dlt>>=1) Bv+=__shfl_xor(Bv,dlt);
    if(o==0) klg[g] = 0.5f*C*Sln + Bv;
}

// ---------------- per-graph MLP head -> pred ----------------
__global__ __launch_bounds__(256) void k_pred(cfp sub, cfp Wp1, cfp bp1, cfp Wp2, cfp bp2,
                                              cfp Wp3, cfp bp3, fpt outp){
    __shared__ float ssub[H];
    __shared__ float sh1[256];
    __shared__ float sh2[128];
    int g = blockIdx.x; int tid = threadIdx.x;
    if(tid<H) ssub[tid] = sub[(size_t)g*H+tid];
    __syncthreads();
    float a = bp1[tid];
    for(int o=0;o<H;o++) a += ssub[o]*Wp1[(size_t)o*256+tid];
    sh1[tid]=relu_(a);
    __syncthreads();
    if(tid<128){
        float b = bp2[tid];
        for(int i=0;i<256;i++) b += sh1[i]*Wp2[(size_t)i*128+tid];
        sh2[tid]=relu_(b);
    }
    __syncthreads();
    if(tid<64){
        float s = sh2[tid]*Wp3[tid] + sh2[tid+64]*Wp3[tid+64];
        #pragma unroll
        for(int dlt=32;dlt>0;dlt>>=1) s+=__shfl_xor(s,dlt);
        if(tid==0) outp[g]=sigmoid_(s+bp3[0]);
    }
}

// ---------------- kl.mean + preserve_rate ----------------
__global__ void k_final(cfp klg, cfp pres, fpt outp){
    float s = 0.f;
    for(int i=threadIdx.x;i<NGRAPH;i+=256) s+=klg[i];
    __shared__ float red[4];
    #pragma unroll
    for(int dlt=32;dlt>0;dlt>>=1) s+=__shfl_xor(s,dlt);
    int wid = threadIdx.x>>6;
    if((threadIdx.x&63)==0) red[wid]=s;
    __syncthreads();
    if(threadIdx.x==0){
        float tot = red[0]+red[1]+red[2]+red[3];
        outp[NGRAPH]   = tot/(float)(NGRAPH*H);
        outp[NGRAPH+1] = pres[0]/(float)NFRAG;
    }
}

extern "C" void kernel_launch(void* const* d_in, const int* in_sizes, int n_in,
                              void* d_out, int out_size, void* d_ws, size_t ws_size,
                              hipStream_t stream) {
    (void)in_sizes; (void)n_in; (void)out_size; (void)ws_size;
    const float* x        =(const float*)d_in[0];
    const float* edge_attr=(const float*)d_in[1];
    const float* noise    =(const float*)d_in[2];
    const float* W0       =(const float*)d_in[3];
    const float* b0       =(const float*)d_in[4];
    const float* We1      =(const float*)d_in[5];
    const float* be1      =(const float*)d_in[6];
    const float* We2      =(const float*)d_in[7];
    const float* be2      =(const float*)d_in[8];
    const float* root     =(const float*)d_in[9];
    const float* conv_b   =(const float*)d_in[10];
    const float* Wm       =(const float*)d_in[11];
    const float* bm       =(const float*)d_in[12];
    const float* Wc1      =(const float*)d_in[13];
    const float* bc1      =(const float*)d_in[14];
    const float* bng      =(const float*)d_in[15];
    const float* bnb      =(const float*)d_in[16];
    const float* Wc2      =(const float*)d_in[17];
    const float* bc2      =(const float*)d_in[18];
    const float* Wp1      =(const float*)d_in[19];
    const float* bp1      =(const float*)d_in[20];
    const float* Wp2      =(const float*)d_in[21];
    const float* bp2      =(const float*)d_in[22];
    const float* Wp3      =(const float*)d_in[23];
    const float* bp3      =(const float*)d_in[24];
    const int*   ei       =(const int*)d_in[25];

    float* ws = (float*)d_ws;
    const size_t NHS = (size_t)NN*HS;
    float* out_a  = ws;                          // 14.4 MB
    float* agg    = out_a + NHS;                 // 14.4 MB
    float* tbuf   = agg + NHS;                   // 6 MB
    float* tP     = tbuf + (size_t)NE*EDIM;      // 7.2 MB
    float* frag   = tP + (size_t)NE*12;          // 2.64 MB
    float* zbuf   = frag + (size_t)NFRAG*H;      // 2.64 MB
    float* wv     = zbuf + (size_t)NFRAG*H;      // 15000
    float* sub    = wv + NFRAG;                  // 66000
    float* klg    = sub + (size_t)NGRAPH*H;      // 1500
    float* WextP  = klg + NGRAPH;                // 25344
    float* colpart= WextP + 11*48*48;            // 52800
    float* colstat= colpart + 300*176;           // 176 (+pad)
    int*   rowptr = (int*)(colstat + 176 + 16);  // 75001
    int*   eidx   = rowptr + (NN+1);             // 150000
    int*   srcP   = eidx + NE;                   // 150000
    int*   bsum   = srcP + NE;                   // 128
    int*   incl   = bsum + 128;                  // 75000
    int*   cnt    = incl + NN;                   // 75000 (zeroed)
    int*   cur    = cnt + NN;                    // 75000 (zeroed)
    float* pres   = (float*)(cur + NN);          // 4     (zeroed)

    hipMemsetAsync(cnt, 0, (size_t)(2*NN)*sizeof(int) + 4*sizeof(float), stream);

    const int nb_n  = (NN + 255)/256;
    const int nb_e  = (NE + 255)/256;
    const int nb_f  = (NFRAG + 255)/256;
    const int nblk  = (NN + 1023)/1024;
    const int nb_c  = (NN + NBC-1)/NBC;
    const int nb_r  = (NN + 63)/64;

    // CSR build (edges are iteration-invariant), canonical order via sort
    k_hist   <<<nb_e,256,0,stream>>>(ei, cnt);
    k_scan1  <<<nblk,1024,0,stream>>>(cnt, incl, bsum);
    k_scan2  <<<1,64,0,stream>>>(bsum, nblk);
    k_scan3  <<<nblk,1024,0,stream>>>(incl, bsum, rowptr);
    k_scatter<<<nb_e,256,0,stream>>>(ei, rowptr, cur, eidx);
    k_sortcsr<<<nb_n,256,0,stream>>>(rowptr, eidx);

    k_edge <<<nb_e,256,0,stream>>>(edge_attr, We1, be1, tbuf);
    k_perm <<<nb_e,256,0,stream>>>(eidx, ei, tbuf, srcP, tP);
    k_wprep<<<(11*48*48+255)/256,256,0,stream>>>(We2, be2, WextP);
    k_in   <<<nb_n,256,0,stream>>>(x, W0, b0, out_a);

    for(int it=0; it<3; ++it){
        k_Ragg<<<nb_r,256,0,stream>>>(out_a, rowptr, srcP, tP, WextP, agg);
        k_comb<<<nb_c,256,0,stream>>>(out_a, agg, root, conv_b, Wm, bm);
    }

    k_frag  <<<300,256,0,stream>>>(out_a, x, Wc1, bc1, frag, zbuf, colpart);
    k_colred<<<176,64,0,stream>>>(colpart, colstat);
    k_bnw   <<<nb_f,256,0,stream>>>(zbuf, colstat, bng, bnb, Wc2, bc2, wv, pres);
    k_graph <<<NGRAPH,64,0,stream>>>(frag, wv, noise, sub, klg);
    k_pred  <<<NGRAPH,256,0,stream>>>(sub, Wp1, bp1, Wp2, bp2, Wp3, bp3, (float*)d_out);
    k_final <<<1,256,0,stream>>>(klg, pres, (float*)d_out);
}